// Round 1
// baseline (156.576 us; speedup 1.0000x reference)
//
#include <hip/hip_runtime.h>
#include <math.h>

#define CC 512
#define CB 128
#define BB 32
#define HW 4096

// ---- kernel 1: global average pool over H*W per (b,c) row ----
__global__ __launch_bounds__(256) void se_pool(const float* __restrict__ in,
                                               float* __restrict__ s) {
    int bc = blockIdx.x;  // 0 .. B*C-1
    const float4* row = (const float4*)(in + (size_t)bc * HW);
    int t = threadIdx.x;
    float acc = 0.f;
#pragma unroll
    for (int i = 0; i < 4; ++i) {
        float4 v = row[t + i * 256];
        acc += v.x + v.y + v.z + v.w;
    }
#pragma unroll
    for (int off = 32; off >= 1; off >>= 1)
        acc += __shfl_xor(acc, off, 64);
    __shared__ float red[4];
    if ((t & 63) == 0) red[t >> 6] = acc;
    __syncthreads();
    if (t == 0) {
        s[bc] = (red[0] + red[1] + red[2] + red[3]) * (1.0f / HW);
    }
}

// ---- kernel 2: h[b][k] = relu(s[b,:] . w1[k,:] + b1[k]) ; one block per k ----
__global__ __launch_bounds__(256) void se_h(const float* __restrict__ s,
                                            const float* __restrict__ w1,
                                            const float* __restrict__ b1,
                                            float* __restrict__ h) {
    int k = blockIdx.x;  // 0..127
    __shared__ float wrow[CC];
    int t = threadIdx.x;
    wrow[t]       = w1[k * CC + t];
    wrow[t + 256] = w1[k * CC + t + 256];
    __syncthreads();
    int b = t >> 3;       // 0..31
    int p = t & 7;        // 0..7 : split the 512-dot 8 ways
    const float* srow = s + b * CC + p * 64;
    const float* wp   = wrow + p * 64;
    float acc = 0.f;
#pragma unroll
    for (int j = 0; j < 64; ++j) acc += srow[j] * wp[j];
    acc += __shfl_xor(acc, 1, 64);
    acc += __shfl_xor(acc, 2, 64);
    acc += __shfl_xor(acc, 4, 64);
    if (p == 0) {
        float v = acc + b1[k];
        h[b * CB + k] = v > 0.f ? v : 0.f;
    }
}

// ---- kernel 3: batchnorm over batch dim (training-mode biased var), in place ----
__global__ __launch_bounds__(128) void se_bn(float* __restrict__ h,
                                             const float* __restrict__ gamma,
                                             const float* __restrict__ beta) {
    int k = threadIdx.x;  // 0..127, owns column k
    float sum = 0.f, sumsq = 0.f;
#pragma unroll
    for (int b = 0; b < BB; ++b) {
        float v = h[b * CB + k];
        sum += v;
        sumsq += v * v;
    }
    float mu  = sum * (1.0f / BB);
    float var = sumsq * (1.0f / BB) - mu * mu;
    float sc  = gamma[k] * rsqrtf(var + 1e-5f);
    float sh  = beta[k] - mu * sc;
#pragma unroll
    for (int b = 0; b < BB; ++b)
        h[b * CB + k] = h[b * CB + k] * sc + sh;
}

// ---- kernel 4: g = sigmoid(hn[b,:] . w2[c,:] + b2[c]); out = in * g ----
__global__ __launch_bounds__(256) void se_mul(const float* __restrict__ in,
                                              const float* __restrict__ hn,
                                              const float* __restrict__ w2,
                                              const float* __restrict__ b2,
                                              float* __restrict__ out) {
    int bc = blockIdx.x;
    int b = bc >> 9;    // /512
    int c = bc & 511;
    // every thread redundantly computes the 128-length dot (uniform addresses,
    // L2-resident operands -> negligible vs the 32 KB of HBM traffic below)
    const float4* hv = (const float4*)(hn + b * CB);
    const float4* wv = (const float4*)(w2 + c * CB);
    float acc = 0.f;
#pragma unroll
    for (int i = 0; i < 32; ++i) {
        float4 a = hv[i];
        float4 w = wv[i];
        acc += a.x * w.x + a.y * w.y + a.z * w.z + a.w * w.w;
    }
    float g = 1.0f / (1.0f + expf(-(acc + b2[c])));

    const float4* iv = (const float4*)(in + (size_t)bc * HW);
    float4* ov       = (float4*)(out + (size_t)bc * HW);
    int t = threadIdx.x;
#pragma unroll
    for (int i = 0; i < 4; ++i) {
        float4 v = iv[t + i * 256];
        v.x *= g; v.y *= g; v.z *= g; v.w *= g;
        ov[t + i * 256] = v;
    }
}

extern "C" void kernel_launch(void* const* d_in, const int* in_sizes, int n_in,
                              void* d_out, int out_size, void* d_ws, size_t ws_size,
                              hipStream_t stream) {
    const float* in    = (const float*)d_in[0];
    const float* w1    = (const float*)d_in[1];
    const float* b1    = (const float*)d_in[2];
    const float* gamma = (const float*)d_in[3];
    const float* beta  = (const float*)d_in[4];
    const float* w2    = (const float*)d_in[5];
    const float* b2    = (const float*)d_in[6];
    float* out = (float*)d_out;

    float* s = (float*)d_ws;        // 32*512 floats
    float* h = s + BB * CC;         // 32*128 floats

    se_pool<<<BB * CC, 256, 0, stream>>>(in, s);
    se_h<<<CB, 256, 0, stream>>>(s, w1, b1, h);
    se_bn<<<1, CB, 0, stream>>>(h, gamma, beta);
    se_mul<<<BB * CC, 256, 0, stream>>>(in, h, w2, b2, out);
}

// Round 3
// 128.373 us; speedup vs baseline: 1.2197x; 1.2197x over previous
//
#include <hip/hip_runtime.h>
#include <math.h>

#define CC 512
#define CB 128
#define BB 32
#define HW 4096

typedef float f32x4 __attribute__((ext_vector_type(4)));

// ---- kernel 1: global average pool over H*W per (b,c) row ----
// Normal (caching) loads: we WANT the input resident in L3 for se_mul's re-read.
__global__ __launch_bounds__(256) void se_pool(const float* __restrict__ in,
                                               float* __restrict__ s) {
    int bc = blockIdx.x;  // 0 .. B*C-1
    const f32x4* row = (const f32x4*)(in + (size_t)bc * HW);
    int t = threadIdx.x;
    float acc = 0.f;
#pragma unroll
    for (int i = 0; i < 4; ++i) {
        f32x4 v = row[t + i * 256];
        acc += v.x + v.y + v.z + v.w;
    }
#pragma unroll
    for (int off = 32; off >= 1; off >>= 1)
        acc += __shfl_xor(acc, off, 64);
    __shared__ float red[4];
    if ((t & 63) == 0) red[t >> 6] = acc;
    __syncthreads();
    if (t == 0) {
        s[bc] = (red[0] + red[1] + red[2] + red[3]) * (1.0f / HW);
    }
}

// ---- kernel 2: h[b][k] = relu(s[b,:] . w1[k,:] + b1[k]) ; one block per k ----
__global__ __launch_bounds__(256) void se_h(const float* __restrict__ s,
                                            const float* __restrict__ w1,
                                            const float* __restrict__ b1,
                                            float* __restrict__ h) {
    int k = blockIdx.x;  // 0..127
    __shared__ float wrow[CC];
    int t = threadIdx.x;
    wrow[t]       = w1[k * CC + t];
    wrow[t + 256] = w1[k * CC + t + 256];
    __syncthreads();
    int b = t >> 3;       // 0..31
    int p = t & 7;        // 0..7 : split the 512-dot 8 ways
    const float* srow = s + b * CC + p * 64;
    const float* wp   = wrow + p * 64;
    float acc = 0.f;
#pragma unroll
    for (int j = 0; j < 64; ++j) acc += srow[j] * wp[j];
    acc += __shfl_xor(acc, 1, 64);
    acc += __shfl_xor(acc, 2, 64);
    acc += __shfl_xor(acc, 4, 64);
    if (p == 0) {
        float v = acc + b1[k];
        h[b * CB + k] = v > 0.f ? v : 0.f;
    }
}

// ---- kernel 3: batchnorm over batch dim (training-mode biased var), in place ----
__global__ __launch_bounds__(128) void se_bn(float* __restrict__ h,
                                             const float* __restrict__ gamma,
                                             const float* __restrict__ beta) {
    int k = threadIdx.x;  // 0..127, owns column k
    float sum = 0.f, sumsq = 0.f;
#pragma unroll
    for (int b = 0; b < BB; ++b) {
        float v = h[b * CB + k];
        sum += v;
        sumsq += v * v;
    }
    float mu  = sum * (1.0f / BB);
    float var = sumsq * (1.0f / BB) - mu * mu;
    float sc  = gamma[k] * rsqrtf(var + 1e-5f);
    float sh  = beta[k] - mu * sc;
#pragma unroll
    for (int b = 0; b < BB; ++b)
        h[b * CB + k] = h[b * CB + k] * sc + sh;
}

// ---- kernel 4: g = sigmoid(hn[b,:] . w2[c,:] + b2[c]); out = in * g ----
// Reversed block order: L3 holds the TAIL of the input after se_pool's stream;
// read most-recently-cached rows first. Non-temporal stores keep the output
// from evicting the cached input.
__global__ __launch_bounds__(256) void se_mul(const float* __restrict__ in,
                                              const float* __restrict__ hn,
                                              const float* __restrict__ w2,
                                              const float* __restrict__ b2,
                                              float* __restrict__ out) {
    int bc = (BB * CC - 1) - blockIdx.x;   // reverse order
    int b = bc >> 9;    // /512
    int c = bc & 511;
    // redundant per-block 128-dot: uniform addresses, L2-resident, hidden by
    // the thousands of concurrently-resident blocks
    const f32x4* hv = (const f32x4*)(hn + b * CB);
    const f32x4* wv = (const f32x4*)(w2 + c * CB);
    float acc = 0.f;
#pragma unroll
    for (int i = 0; i < 32; ++i) {
        f32x4 a = hv[i];
        f32x4 w = wv[i];
        acc += a.x * w.x + a.y * w.y + a.z * w.z + a.w * w.w;
    }
    float g = 1.0f / (1.0f + expf(-(acc + b2[c])));

    const f32x4* iv = (const f32x4*)(in + (size_t)bc * HW);
    f32x4* ov       = (f32x4*)(out + (size_t)bc * HW);
    int t = threadIdx.x;
#pragma unroll
    for (int i = 0; i < 4; ++i) {
        f32x4 v = iv[t + i * 256];
        v.x *= g; v.y *= g; v.z *= g; v.w *= g;
        __builtin_nontemporal_store(v, &ov[t + i * 256]);
    }
}

extern "C" void kernel_launch(void* const* d_in, const int* in_sizes, int n_in,
                              void* d_out, int out_size, void* d_ws, size_t ws_size,
                              hipStream_t stream) {
    const float* in    = (const float*)d_in[0];
    const float* w1    = (const float*)d_in[1];
    const float* b1    = (const float*)d_in[2];
    const float* gamma = (const float*)d_in[3];
    const float* beta  = (const float*)d_in[4];
    const float* w2    = (const float*)d_in[5];
    const float* b2    = (const float*)d_in[6];
    float* out = (float*)d_out;

    float* s = (float*)d_ws;        // 32*512 floats
    float* h = s + BB * CC;         // 32*128 floats

    se_pool<<<BB * CC, 256, 0, stream>>>(in, s);
    se_h<<<CB, 256, 0, stream>>>(s, w1, b1, h);
    se_bn<<<1, CB, 0, stream>>>(h, gamma, beta);
    se_mul<<<BB * CC, 256, 0, stream>>>(in, h, w2, b2, out);
}